// Round 4
// baseline (483.546 us; speedup 1.0000x reference)
//
#include <hip/hip_runtime.h>

#define NGR 8192
#define NN 54
#define NE 144
#define FN 18
#define FE 5
#define HD 48
#define NOUT 80
#define NL 3
#define HS 56    // h/agg row stride (shorts): 112B, 2-way banks
#define MS 72    // m row stride (shorts): 144B
#define TS 152   // m_t row stride (shorts): 304B
#define NFRAG 102

typedef short v8s __attribute__((ext_vector_type(8)));
typedef float v4f __attribute__((ext_vector_type(4)));

#define MFMA(a, b, c) __builtin_amdgcn_mfma_f32_16x16x32_bf16((a), (b), (c), 0, 0, 0)

static __device__ __forceinline__ float mish_f(float x) {
  float t = __expf(x);
  float s = 1.0f + t;
  float s2 = s * s;
  float r = (s2 - 1.0f) * __builtin_amdgcn_rcpf(s2 + 1.0f);
  return (x > 20.0f) ? x : x * r;
}
static __device__ __forceinline__ short f2b(float x) {  // fp32->bf16 RNE
  union { float f; unsigned u; } v; v.f = x;
  unsigned r = v.u + 0x7FFFu + ((v.u >> 16) & 1u);
  return (short)(r >> 16);
}
static __device__ __forceinline__ float b2f(short s) {
  union { unsigned u; float f; } v; v.u = ((unsigned)(unsigned short)s) << 16;
  return v.f;
}
static __device__ __forceinline__ unsigned pk2(float a, float b) {  // two bf16 in one u32
  return (unsigned)(unsigned short)f2b(a) | ((unsigned)(unsigned short)f2b(b) << 16);
}

// ---------------- setup: weight fragment prepack + folded msg bias (102 frags, round-2-proven size) ----------------
__global__ void gnn_setup(const float* __restrict__ w_node,
                          const float* __restrict__ w_edge,
                          const float* __restrict__ b_edge,
                          const float* __restrict__ msg_w1,
                          const float* __restrict__ msg_b1,
                          const float* __restrict__ msg_w2,
                          const float* __restrict__ upd_w1,
                          const float* __restrict__ upd_w2,
                          float* __restrict__ mb1, short* __restrict__ frags) {
  const int t = threadIdx.x;
  if (blockIdx.x == 0) {
    for (int idx = t; idx < NL * HD; idx += 256) {
      int l = idx / HD, c = idx % HD;
      float s = msg_b1[l * HD + c];
      for (int k = 0; k < HD; ++k)
        s += b_edge[k] * msg_w1[(l * 144 + 96 + k) * HD + c];
      mb1[idx] = s;
    }
  }
  // frag f, lane, elem j holds W[ks*32 + (lane>>4)*8 + j][ct*16 + (lane&15)]
  for (int eid = blockIdx.x * 256 + t; eid < NFRAG * 512; eid += gridDim.x * 256) {
    int f = eid >> 9, r = eid & 511;
    int lane = r >> 3, j = r & 7;
    int kk = ((lane >> 4) << 3) + j;
    int colq = lane & 15;
    float val = 0.f;
    if (f < 3) {                          // w_node (K=18 pad 32), ct=f
      int c = f * 16 + colq;
      if (kk < FN) val = w_node[kk * HD + c];
    } else {
      int g = f - 3, l = g / 33, o = g % 33;
      if (o < 9) {                        // msg_w1 rows 0..95
        int ks = o / 3, ct = o % 3, c = ct * 16 + colq, k = ks * 32 + kk;
        val = msg_w1[(l * 144 + k) * HD + c];
      } else if (o < 12) {                // W_eff = w_edge @ msg_w1[96:144] (K=5 pad 32)
        int ct = o - 9, c = ct * 16 + colq;
        if (kk < FE) {
          float s = 0.f;
          for (int k2 = 0; k2 < HD; ++k2)
            s += w_edge[kk * HD + k2] * msg_w1[(l * 144 + 96 + k2) * HD + c];
          val = s;
        }
      } else if (o < 18) {                // msg_w2 (K=48 pad 64)
        int oo = o - 12, ks = oo / 3, ct = oo % 3, c = ct * 16 + colq, k = ks * 32 + kk;
        if (k < HD) val = msg_w2[(l * HD + k) * HD + c];
      } else if (o < 27) {                // upd_w1 (K=96)
        int oo = o - 18, ks = oo / 3, ct = oo % 3, c = ct * 16 + colq, k = ks * 32 + kk;
        val = upd_w1[(l * 96 + k) * HD + c];
      } else {                            // upd_w2 (K=48 pad 64)
        int oo = o - 27, ks = oo / 3, ct = oo % 3, c = ct * 16 + colq, k = ks * 32 + kk;
        if (k < HD) val = upd_w2[(l * HD + k) * HD + c];
      }
    }
    frags[eid] = f2b(val);
  }
}

// ---------------- main: one block (4 waves) per graph ----------------
__global__ __launch_bounds__(256, 4) void gnn_main(
    const float* __restrict__ nf, const float* __restrict__ efx,
    const float* __restrict__ b_node,
    const float* __restrict__ msg_b2,
    const float* __restrict__ upd_b1, const float* __restrict__ upd_b2,
    const float* __restrict__ ln_g, const float* __restrict__ ln_b,
    const float* __restrict__ w_out1, const float* __restrict__ b_out1,
    const float* __restrict__ w_out2, const float* __restrict__ b_out2,
    const int* __restrict__ edge_index,
    const float* __restrict__ mb1, const short* __restrict__ frags,
    float* __restrict__ out)
{
  __shared__ __align__(16) short h_s[NN][HS];        // 6048 B
  __shared__ __align__(16) short agg_s[NN][HS];      // 6048 B
  __shared__ __align__(16) short m_s[80][MS];        // 11520 B
  __shared__ __align__(16) short m_t[48 * TS + 8];   // 14608 B (row48 head = read guard)
  __shared__ int dst_s[NE];
  __shared__ float psum[96], pmax[96], pooled[96], o1[NOUT];

  const int b = blockIdx.x;
  const int t = threadIdx.x;
  const int lane = t & 63;
  const int w = t >> 6;
  const int lx = lane & 15;
  const int lg = lane >> 4;
  const int koff = lg << 3;
  const int lg4 = lg << 2;

#define LD8(f) (*(const v8s*)(frags + ((size_t)(f) << 9) + (lane << 3)))

  // ---- stage ----
  if (t < NE) dst_s[t] = edge_index[NE + t];
  for (int idx = t; idx < 64 * 32; idx += 256) {     // nf (K=18 pad 32); rows 54..63 zero
    int r = idx >> 5, c = idx & 31;
    m_s[r][c] = (r < NN && c < FN) ? f2b(nf[(size_t)b * (NN * FN) + r * FN + c]) : (short)0;
  }
  for (int idx = t; idx < 80 * 16; idx += 256)       // m K-pad cols 48..63 (never rewritten)
    m_s[idx >> 4][48 + (idx & 15)] = 0;
  for (int idx = t; idx < 48 * 8; idx += 256)        // m_t pad cols 144..151
    m_t[(idx >> 3) * TS + 144 + (idx & 7)] = 0;
  if (t < 8) m_t[48 * TS + t] = 0;                   // tail guard

  // ---- per-wave edge tiles & register frags ----
  const int mt0 = w, mt2 = 5 + w;
  int rs0 = edge_index[mt0 * 16 + lx] * HS, rd0 = edge_index[NE + mt0 * 16 + lx] * HS;
  int rs1 = 0, rd1 = 0;
  if (w == 0) { rs1 = edge_index[64 + lx] * HS; rd1 = edge_index[NE + 64 + lx] * HS; }
  int rs2 = edge_index[mt2 * 16 + lx] * HS, rd2 = edge_index[NE + mt2 * 16 + lx] * HS;

  auto ldef = [&](int mt) -> v8s {   // ef A-frag: lg==0 lanes hold ef[e][0..4]
    v8s r = {0, 0, 0, 0, 0, 0, 0, 0};
    if (lg == 0) {
      const float* ep = efx + (size_t)b * (NE * FE) + (mt * 16 + lx) * FE;
      r[0] = f2b(ep[0]); r[1] = f2b(ep[1]); r[2] = f2b(ep[2]);
      r[3] = f2b(ep[3]); r[4] = f2b(ep[4]);
    }
    return r;
  };
  v8s aef0 = ldef(mt0);
  v8s aef1 = (w == 0) ? ldef(4) : (v8s){0,0,0,0,0,0,0,0};
  v8s aef2 = ldef(mt2);

  __syncthreads();

  const short* h0 = &h_s[0][0];
  const short* g0 = &agg_s[0][0];

  // ---- input proj (round-2 verbatim; A = nf rows, B = w_node frags) ----
  {
    v8s a = *(const v8s*)(&m_s[w * 16 + lx][koff]);
    const int orow = w * 16 + lg4;
    #pragma unroll
    for (int nt = 0; nt < 3; ++nt) {
      float bb = b_node[nt * 16 + lx];
      v4f c = {bb, bb, bb, bb};
      c = MFMA(a, LD8(nt), c);
      #pragma unroll
      for (int r = 0; r < 4; ++r)
        if (orow + r < NN) h_s[orow + r][nt * 16 + lx] = f2b(mish_f(c[r]));
    }
  }
  __syncthreads();

  for (int l = 0; l < NL; ++l) {
    const int FB = 3 + l * 33;
    float bm1[3], bm2[3];
    #pragma unroll
    for (int nt = 0; nt < 3; ++nt) {
      bm1[nt] = mb1[l * HD + nt * 16 + lx];
      bm2[nt] = msg_b2[(size_t)l * HD + nt * 16 + lx];
    }

    // ---- msg1 + msg2 per tile (slot reuse; same-wave in-order LDS) ----
    auto do_msg = [&](int mt, int slot, v8s aef, int rs, int rd) {
      v4f c0 = {bm1[0], bm1[0], bm1[0], bm1[0]};
      v4f c1 = {bm1[1], bm1[1], bm1[1], bm1[1]};
      v4f c2 = {bm1[2], bm1[2], bm1[2], bm1[2]};
      c0 = MFMA(aef, LD8(FB + 9),  c0);
      c1 = MFMA(aef, LD8(FB + 10), c1);
      c2 = MFMA(aef, LD8(FB + 11), c2);
      #pragma unroll
      for (int ks = 0; ks < 3; ++ks) {
        int kk = ks * 32 + koff;
        const short* p = (kk < HD) ? (h0 + rs + kk) : (h0 + rd + (kk - HD));
        v8s a = *(const v8s*)p;
        c0 = MFMA(a, LD8(FB + ks * 3 + 0), c0);
        c1 = MFMA(a, LD8(FB + ks * 3 + 1), c1);
        c2 = MFMA(a, LD8(FB + ks * 3 + 2), c2);
      }
      const int orow = slot + lg4;
      #pragma unroll
      for (int r = 0; r < 4; ++r) {
        m_s[orow + r][lx]      = f2b(mish_f(c0[r]));
        m_s[orow + r][16 + lx] = f2b(mish_f(c1[r]));
        m_s[orow + r][32 + lx] = f2b(mish_f(c2[r]));
      }
      // msg2: A = m rows (just written, same wave), B = msg_w2 frags; out -> m_t transposed
      v8s a0 = *(const v8s*)(&m_s[slot + lx][koff]);
      v8s a1 = *(const v8s*)(&m_s[slot + lx][32 + koff]);
      #pragma unroll
      for (int nt = 0; nt < 3; ++nt) {
        v4f c = {bm2[nt], bm2[nt], bm2[nt], bm2[nt]};
        c = MFMA(a0, LD8(FB + 12 + nt), c);
        c = MFMA(a1, LD8(FB + 15 + nt), c);
        uint2 u;
        u.x = pk2(mish_f(c[0]), mish_f(c[1]));
        u.y = pk2(mish_f(c[2]), mish_f(c[3]));
        *(uint2*)(&m_t[(nt * 16 + lx) * TS + mt * 16 + lg4]) = u;
      }
    };
    do_msg(mt0, w * 16, aef0, rs0, rd0);
    if (w == 0) do_msg(4, 64, aef1, rs1, rd1);
    do_msg(mt2, w * 16, aef2, rs2, rd2);
    __syncthreads();   // barrier 1: m_t complete

    const int node = w * 16 + lx;
    // ---- agg via MFMA: agg^T = m_t · S^T; S-frags built in regs from dst_s ----
    {
      v8s sfr[5];
      #pragma unroll
      for (int kt = 0; kt < 5; ++kt) {
        v8s sv = {0, 0, 0, 0, 0, 0, 0, 0};
        #pragma unroll
        for (int j = 0; j < 8; ++j) {
          int e = kt * 32 + koff + j;
          if (e < NE && dst_s[e] == node) sv[j] = (short)0x3F80;  // bf16 1.0
        }
        sfr[kt] = sv;
      }
      #pragma unroll
      for (int ct = 0; ct < 3; ++ct) {
        v4f c = {0.f, 0.f, 0.f, 0.f};
        #pragma unroll
        for (int kt = 0; kt < 5; ++kt) {
          v8s a = *(const v8s*)(&m_t[(ct * 16 + lx) * TS + kt * 32 + koff]);
          c = MFMA(a, sfr[kt], c);
        }
        if (node < NN) {
          uint2 u; u.x = pk2(c[0], c[1]); u.y = pk2(c[2], c[3]);
          *(uint2*)(&agg_s[node][ct * 16 + lg4]) = u;
        }
      }
    }
    // ---- upd1 (same wave; clamped reads for fake nodes) ----
    {
      const int nrd = (node < NN) ? node : 0;
      v4f c0 = {upd_b1[l*HD + lx],      upd_b1[l*HD + lx],      upd_b1[l*HD + lx],      upd_b1[l*HD + lx]};
      v4f c1 = {upd_b1[l*HD + 16 + lx], upd_b1[l*HD + 16 + lx], upd_b1[l*HD + 16 + lx], upd_b1[l*HD + 16 + lx]};
      v4f c2 = {upd_b1[l*HD + 32 + lx], upd_b1[l*HD + 32 + lx], upd_b1[l*HD + 32 + lx], upd_b1[l*HD + 32 + lx]};
      #pragma unroll
      for (int ks = 0; ks < 3; ++ks) {
        int kk = ks * 32 + koff;
        const short* p = (kk < HD) ? (h0 + nrd * HS + kk) : (g0 + nrd * HS + (kk - HD));
        v8s a = *(const v8s*)p;
        c0 = MFMA(a, LD8(FB + 18 + ks * 3 + 0), c0);
        c1 = MFMA(a, LD8(FB + 18 + ks * 3 + 1), c1);
        c2 = MFMA(a, LD8(FB + 18 + ks * 3 + 2), c2);
      }
      const int orow = w * 16 + lg4;
      #pragma unroll
      for (int r = 0; r < 4; ++r) {
        m_s[orow + r][lx]      = f2b(mish_f(c0[r]));
        m_s[orow + r][16 + lx] = f2b(mish_f(c1[r]));
        m_s[orow + r][32 + lx] = f2b(mish_f(c2[r]));
      }
      // ---- upd2 + residual + LN (same wave) ----
      v8s a0 = *(const v8s*)(&m_s[node][koff]);
      v8s a1 = *(const v8s*)(&m_s[node][32 + koff]);
      v4f cc[3];
      #pragma unroll
      for (int nt = 0; nt < 3; ++nt) {
        float bb = upd_b2[(size_t)l * HD + nt * 16 + lx];
        v4f c = {bb, bb, bb, bb};
        c = MFMA(a0, LD8(FB + 27 + nt), c);
        c = MFMA(a1, LD8(FB + 30 + nt), c);
        cc[nt] = c;
      }
      float x[3][4], s[4], q[4];
      #pragma unroll
      for (int r = 0; r < 4; ++r) {
        int rr = (orow + r < NN) ? (orow + r) : 0;
        #pragma unroll
        for (int nt = 0; nt < 3; ++nt)
          x[nt][r] = cc[nt][r] + b2f(h_s[rr][nt * 16 + lx]);
        s[r] = x[0][r] + x[1][r] + x[2][r];
        q[r] = fmaf(x[0][r], x[0][r], fmaf(x[1][r], x[1][r], x[2][r] * x[2][r]));
      }
      #pragma unroll
      for (int mask = 1; mask <= 8; mask <<= 1)
        #pragma unroll
        for (int r = 0; r < 4; ++r) {
          s[r] += __shfl_xor(s[r], mask);
          q[r] += __shfl_xor(q[r], mask);
        }
      float* onode = out + (size_t)NGR * NOUT + (size_t)b * (NN * HD);
      #pragma unroll
      for (int r = 0; r < 4; ++r) {
        float mu = s[r] * (1.f / HD);
        float var = q[r] * (1.f / HD) - mu * mu;
        float rsg = rsqrtf(var + 1e-5f);
        int row = orow + r;
        #pragma unroll
        for (int nt = 0; nt < 3; ++nt) {
          float y = (x[nt][r] - mu) * rsg * ln_g[l * HD + nt * 16 + lx] + ln_b[l * HD + nt * 16 + lx];
          if (row < NN) {
            h_s[row][nt * 16 + lx] = f2b(y);
            if (l == NL - 1) onode[row * HD + nt * 16 + lx] = y;
          }
        }
      }
    }
    __syncthreads();   // barrier 2: h ready for next layer / pooling
  }

  // ---- pooling ----
  if (t < 96) {
    int half = t >= HD;
    int ch = t - half * HD;
    float smv = 0.f, mx = -3.0e38f;
    int n0 = half * 27;
    for (int n = n0; n < n0 + 27; ++n) {
      float v = b2f(h_s[n][ch]);
      smv += v; mx = fmaxf(mx, v);
    }
    psum[t] = smv; pmax[t] = mx;
  }
  __syncthreads();
  if (t < HD) {
    pooled[t] = (psum[t] + psum[HD + t]) * (1.f / NN);
    pooled[HD + t] = fmaxf(pmax[t], pmax[HD + t]);
  }
  __syncthreads();

  // ---- output MLP (fp32) ----
  if (t < NOUT) {
    float a = b_out1[t];
    #pragma unroll 8
    for (int k = 0; k < 2 * HD; ++k) a = fmaf(pooled[k], w_out1[k * NOUT + t], a);
    o1[t] = mish_f(a);
  }
  __syncthreads();
  if (t < NOUT) {
    float a = b_out2[t];
    #pragma unroll 8
    for (int k = 0; k < NOUT; ++k) a = fmaf(o1[k], w_out2[k * NOUT + t], a);
    out[(size_t)b * NOUT + t] = a;
  }
}

extern "C" void kernel_launch(void* const* d_in, const int* in_sizes, int n_in,
                              void* d_out, int out_size, void* d_ws, size_t ws_size,
                              hipStream_t stream) {
  const float* nf     = (const float*)d_in[0];
  const float* ef     = (const float*)d_in[1];
  const float* w_node = (const float*)d_in[2];
  const float* b_node = (const float*)d_in[3];
  const float* w_edge = (const float*)d_in[4];
  const float* b_edge = (const float*)d_in[5];
  const float* msg_w1 = (const float*)d_in[6];
  const float* msg_b1 = (const float*)d_in[7];
  const float* msg_w2 = (const float*)d_in[8];
  const float* msg_b2 = (const float*)d_in[9];
  const float* upd_w1 = (const float*)d_in[10];
  const float* upd_b1 = (const float*)d_in[11];
  const float* upd_w2 = (const float*)d_in[12];
  const float* upd_b2 = (const float*)d_in[13];
  const float* ln_g   = (const float*)d_in[14];
  const float* ln_b   = (const float*)d_in[15];
  const float* w_out1 = (const float*)d_in[16];
  const float* b_out1 = (const float*)d_in[17];
  const float* w_out2 = (const float*)d_in[18];
  const float* b_out2 = (const float*)d_in[19];
  const int* edge_index = (const int*)d_in[20];

  float* mb1   = (float*)d_ws;                   // [0, 768)
  short* frags = (short*)((char*)d_ws + 1024);   // 102*1024 B -> total 105,472 B (round-2-proven)

  gnn_setup<<<32, 256, 0, stream>>>(w_node, w_edge, b_edge, msg_w1, msg_b1,
                                    msg_w2, upd_w1, upd_w2, mb1, frags);
  gnn_main<<<NGR, 256, 0, stream>>>(nf, ef, b_node, msg_b2, upd_b1, upd_b2,
                                    ln_g, ln_b, w_out1, b_out1, w_out2, b_out2,
                                    edge_index, mb1, frags, (float*)d_out);
}